// Round 1
// baseline (122.539 us; speedup 1.0000x reference)
//
#include <hip/hip_runtime.h>

// 16-step spike recurrence, elementwise over x.
// z_t = (v_t > T_t) since (v-T)/(|v|+1) > 0  <=>  v > T  (denominator >= 1).
// Fully unrolled with literal constants; float4 vectorized; grid-stride.

__device__ __constant__ const float kH[16] = {
    -0.73437643f, 3.319645f,   2.1290164f,  3.6901689f,
    3.302721f,    3.2154958f,  2.9151256f,  3.1718695f,
    3.1084518f,   2.6179547f,  2.235003f,   1.2864777f,
    0.52327204f, -0.08344932f, -1.8249638f, 3.0859442f};

__device__ __constant__ const float kD[16] = {
    3.3848417f, -0.07072583f, 3.691287f,   3.3074934f,
    3.2120926f,  2.9196491f,  3.1727686f,  3.1054153f,
    2.621943f,   2.2355895f,  1.2878408f,  0.52468026f,
    0.12632068f, 0.14482783f, 0.3153498f,  0.13054803f};

__device__ __constant__ const float kT[16] = {
    3.1538513f, -1.0211663f,  1.3714716f,  1.0718397f,
    1.0049332f,  0.68078244f, 1.0151638f,  0.8858697f,
    0.4037103f,  0.01490025f, -0.90781677f, -1.6859558f,
    -1.9241625f, -2.0441303f, 0.279356f,   0.1315174f};

__device__ __forceinline__ float spike_chain(float v) {
    float z = 0.0f;
    float out = 0.0f;
#pragma unroll
    for (int t = 0; t < 16; ++t) {
        v = fmaf(-z, kH[t], v);          // v -= z*H[t]  (exact: z is 0 or 1)
        z = (v > kT[t]) ? 1.0f : 0.0f;   // spike
        out = fmaf(z, kD[t], out);       // out += z*D[t]
    }
    return out;
}

__global__ __launch_bounds__(256) void spike_kernel(const float4* __restrict__ x,
                                                    float4* __restrict__ out,
                                                    int n4) {
    int idx = blockIdx.x * blockDim.x + threadIdx.x;
    int stride = gridDim.x * blockDim.x;
    for (int i = idx; i < n4; i += stride) {
        float4 v = x[i];
        float4 o;
        o.x = spike_chain(v.x);
        o.y = spike_chain(v.y);
        o.z = spike_chain(v.z);
        o.w = spike_chain(v.w);
        out[i] = o;
    }
}

extern "C" void kernel_launch(void* const* d_in, const int* in_sizes, int n_in,
                              void* d_out, int out_size, void* d_ws, size_t ws_size,
                              hipStream_t stream) {
    const float* x = (const float*)d_in[0];
    float* out = (float*)d_out;
    int n = in_sizes[0];          // 16*4096*1024 = 67,108,864 (divisible by 4)
    int n4 = n >> 2;

    const int block = 256;
    int grid = (n4 + block - 1) / block;
    if (grid > 2048) grid = 2048;  // grid-stride; ~8 blocks/CU

    spike_kernel<<<grid, block, 0, stream>>>(
        (const float4*)x, (float4*)out, n4);
}